// Round 1
// baseline (127.414 us; speedup 1.0000x reference)
//
#include <hip/hip_runtime.h>

// Problem constants (from reference): N_RNA=20000, N_PROT=5000, D=128, C=4, E=500000
#define DIM 128
#define NCLS 4

// 32 lanes cooperate on one edge: lane l holds floats [4l, 4l+4) of the
// D=128 feature row. 2 edges per wave64. Each wave-wide float4 load reads a
// full 512B row perfectly coalesced.
__global__ __launch_bounds__(256) void decoder_kernel(
    const float* __restrict__ rna,   // [N_RNA, D]
    const float* __restrict__ prot,  // [N_PROT, D]
    const int*   __restrict__ ridx,  // [E]
    const int*   __restrict__ pidx,  // [E]
    const float* __restrict__ wrel,  // [C, D]
    const float* __restrict__ wcls,  // [C, C]
    float*       __restrict__ out,   // [E, C]
    int nEdges)
{
    const int lane32 = threadIdx.x & 31;
    const int hw     = (blockIdx.x * blockDim.x + threadIdx.x) >> 5;  // half-wave id
    const int nhw    = (gridDim.x * blockDim.x) >> 5;

    // Per-lane slice of w_relation (loaded once, lives in registers)
    const float4 w0 = *(const float4*)(wrel + 0 * DIM + lane32 * 4);
    const float4 w1 = *(const float4*)(wrel + 1 * DIM + lane32 * 4);
    const float4 w2 = *(const float4*)(wrel + 2 * DIM + lane32 * 4);
    const float4 w3 = *(const float4*)(wrel + 3 * DIM + lane32 * 4);

    // 4x4 classifier, wave-uniform (compiler scalarizes these loads)
    float wc[16];
#pragma unroll
    for (int i = 0; i < 16; ++i) wc[i] = wcls[i];

    for (int e = hw; e < nEdges; e += nhw) {
        const int ri = ridx[e];
        const int pi = pidx[e];
        const float4 r4 = *(const float4*)(rna  + (size_t)ri * DIM + lane32 * 4);
        const float4 p4 = *(const float4*)(prot + (size_t)pi * DIM + lane32 * 4);

        const float qx = r4.x * p4.x;
        const float qy = r4.y * p4.y;
        const float qz = r4.z * p4.z;
        const float qw = r4.w * p4.w;

        float b0 = qx * w0.x + qy * w0.y + qz * w0.z + qw * w0.w;
        float b1 = qx * w1.x + qy * w1.y + qz * w1.z + qw * w1.w;
        float b2 = qx * w2.x + qy * w2.y + qz * w2.z + qw * w2.w;
        float b3 = qx * w3.x + qy * w3.y + qz * w3.z + qw * w3.w;

        // Butterfly reduction across the 32-lane group
#pragma unroll
        for (int m = 16; m >= 1; m >>= 1) {
            b0 += __shfl_xor(b0, m, 32);
            b1 += __shfl_xor(b1, m, 32);
            b2 += __shfl_xor(b2, m, 32);
            b3 += __shfl_xor(b3, m, 32);
        }

        if (lane32 == 0) {
            float4 o;
            o.x = fmaxf(b0 * wc[0] + b1 * wc[4] + b2 * wc[8]  + b3 * wc[12], 0.0f);
            o.y = fmaxf(b0 * wc[1] + b1 * wc[5] + b2 * wc[9]  + b3 * wc[13], 0.0f);
            o.z = fmaxf(b0 * wc[2] + b1 * wc[6] + b2 * wc[10] + b3 * wc[14], 0.0f);
            o.w = fmaxf(b0 * wc[3] + b1 * wc[7] + b2 * wc[11] + b3 * wc[15], 0.0f);
            *(float4*)(out + (size_t)e * NCLS) = o;
        }
    }
}

extern "C" void kernel_launch(void* const* d_in, const int* in_sizes, int n_in,
                              void* d_out, int out_size, void* d_ws, size_t ws_size,
                              hipStream_t stream) {
    const float* rna  = (const float*)d_in[0];
    const float* prot = (const float*)d_in[1];
    const int*   ridx = (const int*)d_in[2];
    const int*   pidx = (const int*)d_in[3];
    const float* wrel = (const float*)d_in[4];
    const float* wcls = (const float*)d_in[5];
    float*       out  = (float*)d_out;

    const int nEdges = in_sizes[2];  // E = 500000

    // 8192 blocks x 256 thr = 65536 half-waves; ~7.6 edges each (grid-stride).
    // Plenty of waves to hide gather latency on 256 CUs.
    dim3 grid(8192), block(256);
    hipLaunchKernelGGL(decoder_kernel, grid, block, 0, stream,
                       rna, prot, ridx, pidx, wrel, wcls, out, nEdges);
}

// Round 2
// 116.645 us; speedup vs baseline: 1.0923x; 1.0923x over previous
//
#include <hip/hip_runtime.h>

// N_RNA=20000, N_PROT=5000, D=128, C=4, E=500000
#define DIM 128
#define NCLS 4

// 4-value-per-lane reduction across 32 lanes in 6 shuffles.
// Input: lane holds partials for classes 0..3. Output: lane l holds the
// full sum for class cls(l) = 2*(l&1) + ((l>>1)&1), replicated every 4 lanes.
__device__ __forceinline__ float reduce4(float b0, float b1, float b2, float b3, int lane)
{
    const bool lo1 = (lane & 1) == 0;
    float k0 = lo1 ? b0 : b2, s0 = lo1 ? b2 : b0;
    float k1 = lo1 ? b1 : b3, s1 = lo1 ? b3 : b1;
    float v0 = k0 + __shfl_xor(s0, 1, 32);   // even lanes: class0 ; odd: class2
    float v1 = k1 + __shfl_xor(s1, 1, 32);   // even lanes: class1 ; odd: class3
    const bool lo2 = (lane & 2) == 0;
    float k = lo2 ? v0 : v1, s = lo2 ? v1 : v0;
    float v = k + __shfl_xor(s, 2, 32);      // 1 class per lane (lane&3 pattern)
    v += __shfl_xor(v, 4, 32);
    v += __shfl_xor(v, 8, 32);
    v += __shfl_xor(v, 16, 32);
    return v;
}

__global__ __launch_bounds__(256) void decoder_kernel(
    const float* __restrict__ rna,   // [N_RNA, D]
    const float* __restrict__ prot,  // [N_PROT, D]
    const int*   __restrict__ ridx,  // [E]
    const int*   __restrict__ pidx,  // [E]
    const float* __restrict__ wrel,  // [C, D]
    const float* __restrict__ wcls,  // [C, C]
    float*       __restrict__ out,   // [E, C]
    int nEdges)
{
    const int lane32 = threadIdx.x & 31;
    const int hw     = (blockIdx.x * blockDim.x + threadIdx.x) >> 5;
    const int nhw    = (gridDim.x * blockDim.x) >> 5;

    // Per-lane slice of w_relation rows (registers)
    const float4 w0 = *(const float4*)(wrel + 0 * DIM + lane32 * 4);
    const float4 w1 = *(const float4*)(wrel + 1 * DIM + lane32 * 4);
    const float4 w2 = *(const float4*)(wrel + 2 * DIM + lane32 * 4);
    const float4 w3 = *(const float4*)(wrel + 3 * DIM + lane32 * 4);

    float wc[16];
#pragma unroll
    for (int i = 0; i < 16; ++i) wc[i] = wcls[i];

    // Fused weights: wf_j[d] = sum_c wrel[c,d] * wcls[c,j]
    // => out[e,j] = relu( sum_d q[e,d] * wf_j[d] ),  q = r .* p
    float4 wf[4];
#pragma unroll
    for (int j = 0; j < 4; ++j) {
        wf[j].x = wc[j] * w0.x + wc[4 + j] * w1.x + wc[8 + j] * w2.x + wc[12 + j] * w3.x;
        wf[j].y = wc[j] * w0.y + wc[4 + j] * w1.y + wc[8 + j] * w2.y + wc[12 + j] * w3.y;
        wf[j].z = wc[j] * w0.z + wc[4 + j] * w1.z + wc[8 + j] * w2.z + wc[12 + j] * w3.z;
        wf[j].w = wc[j] * w0.w + wc[4 + j] * w1.w + wc[8 + j] * w2.w + wc[12 + j] * w3.w;
    }

    const int cls   = ((lane32 & 1) << 1) | ((lane32 >> 1) & 1);
    const int lelem = lane32 * 4;

    // ILP=2: each half-wave handles 2 contiguous edges per iteration.
    // nEdges is even and e0 is even, so e0 < nEdges implies e0+1 < nEdges.
    for (int e0 = hw * 2; e0 < nEdges; e0 += nhw * 2) {
        const int2 ri2 = *(const int2*)(ridx + e0);
        const int2 pi2 = *(const int2*)(pidx + e0);

        const float4 rA = *(const float4*)(rna  + (size_t)ri2.x * DIM + lelem);
        const float4 pA = *(const float4*)(prot + (size_t)pi2.x * DIM + lelem);
        const float4 rB = *(const float4*)(rna  + (size_t)ri2.y * DIM + lelem);
        const float4 pB = *(const float4*)(prot + (size_t)pi2.y * DIM + lelem);

        float4 qA, qB;
        qA.x = rA.x * pA.x; qA.y = rA.y * pA.y; qA.z = rA.z * pA.z; qA.w = rA.w * pA.w;
        qB.x = rB.x * pB.x; qB.y = rB.y * pB.y; qB.z = rB.z * pB.z; qB.w = rB.w * pB.w;

        float a0 = qA.x * wf[0].x + qA.y * wf[0].y + qA.z * wf[0].z + qA.w * wf[0].w;
        float a1 = qA.x * wf[1].x + qA.y * wf[1].y + qA.z * wf[1].z + qA.w * wf[1].w;
        float a2 = qA.x * wf[2].x + qA.y * wf[2].y + qA.z * wf[2].z + qA.w * wf[2].w;
        float a3 = qA.x * wf[3].x + qA.y * wf[3].y + qA.z * wf[3].z + qA.w * wf[3].w;

        float b0 = qB.x * wf[0].x + qB.y * wf[0].y + qB.z * wf[0].z + qB.w * wf[0].w;
        float b1 = qB.x * wf[1].x + qB.y * wf[1].y + qB.z * wf[1].z + qB.w * wf[1].w;
        float b2 = qB.x * wf[2].x + qB.y * wf[2].y + qB.z * wf[2].z + qB.w * wf[2].w;
        float b3 = qB.x * wf[3].x + qB.y * wf[3].y + qB.z * wf[3].z + qB.w * wf[3].w;

        const float vA = reduce4(a0, a1, a2, a3, lane32);
        const float vB = reduce4(b0, b1, b2, b3, lane32);

        if (lane32 < 4) {
            out[(size_t)e0 * NCLS + cls]       = fmaxf(vA, 0.0f);
            out[(size_t)(e0 + 1) * NCLS + cls] = fmaxf(vB, 0.0f);
        }
    }
}

extern "C" void kernel_launch(void* const* d_in, const int* in_sizes, int n_in,
                              void* d_out, int out_size, void* d_ws, size_t ws_size,
                              hipStream_t stream) {
    const float* rna  = (const float*)d_in[0];
    const float* prot = (const float*)d_in[1];
    const int*   ridx = (const int*)d_in[2];
    const int*   pidx = (const int*)d_in[3];
    const float* wrel = (const float*)d_in[4];
    const float* wcls = (const float*)d_in[5];
    float*       out  = (float*)d_out;

    const int nEdges = in_sizes[2];  // E = 500000

    dim3 grid(8192), block(256);
    hipLaunchKernelGGL(decoder_kernel, grid, block, 0, stream,
                       rna, prot, ridx, pidx, wrel, wcls, out, nEdges);
}

// Round 3
// 107.471 us; speedup vs baseline: 1.1856x; 1.0854x over previous
//
#include <hip/hip_runtime.h>

// N_RNA=20000, N_PROT=5000, D=128, C=4, E=500000
#define DIM 128
#define NCLS 4

// ---------- fp32 -> bf16 (RNE) conversion into workspace ----------
__device__ __forceinline__ unsigned int f2bf_rne(float f) {
    union { float f; unsigned int u; } v; v.f = f;
    return (v.u + 0x7FFFu + ((v.u >> 16) & 1u)) >> 16;
}

__global__ __launch_bounds__(256) void cvt_bf16_kernel(
    const float* __restrict__ src, unsigned int* __restrict__ dst, int nPairs)
{
    // Each output uint packs 2 bf16. Each thread handles 4 uints (8 floats).
    int i = (blockIdx.x * blockDim.x + threadIdx.x) * 4;
    const int stride = gridDim.x * blockDim.x * 4;
    for (; i + 3 < nPairs; i += stride) {
        const float4 a = *(const float4*)(src + i * 2);
        const float4 b = *(const float4*)(src + i * 2 + 4);
        uint4 o;
        o.x = f2bf_rne(a.x) | (f2bf_rne(a.y) << 16);
        o.y = f2bf_rne(a.z) | (f2bf_rne(a.w) << 16);
        o.z = f2bf_rne(b.x) | (f2bf_rne(b.y) << 16);
        o.w = f2bf_rne(b.z) | (f2bf_rne(b.w) << 16);
        *(uint4*)(dst + i) = o;
    }
}

// ---------- helpers ----------
__device__ __forceinline__ float bf2f(unsigned short u) {
    union { unsigned int i; float f; } v; v.i = ((unsigned int)u) << 16; return v.f;
}

// 4-partials -> 1 value/lane reduction over 32 lanes in 6 shuffles.
// Output: lane l holds sum for class cls(l)=2*(l&1)+((l>>1)&1).
__device__ __forceinline__ float reduce4(float b0, float b1, float b2, float b3, int lane)
{
    const bool lo1 = (lane & 1) == 0;
    float k0 = lo1 ? b0 : b2, s0 = lo1 ? b2 : b0;
    float k1 = lo1 ? b1 : b3, s1 = lo1 ? b3 : b1;
    float v0 = k0 + __shfl_xor(s0, 1, 32);
    float v1 = k1 + __shfl_xor(s1, 1, 32);
    const bool lo2 = (lane & 2) == 0;
    float k = lo2 ? v0 : v1, s = lo2 ? v1 : v0;
    float v = k + __shfl_xor(s, 2, 32);
    v += __shfl_xor(v, 4, 32);
    v += __shfl_xor(v, 8, 32);
    v += __shfl_xor(v, 16, 32);
    return v;
}

// Fused weights wf_j[d] = sum_c wrel[c,d]*wcls[c,j]; out[e,j]=relu(sum_d q[d]*wf_j[d])
__device__ __forceinline__ void load_wf(const float* wrel, const float* wcls,
                                        int lane32, float4 wf[4])
{
    const float4 w0 = *(const float4*)(wrel + 0 * DIM + lane32 * 4);
    const float4 w1 = *(const float4*)(wrel + 1 * DIM + lane32 * 4);
    const float4 w2 = *(const float4*)(wrel + 2 * DIM + lane32 * 4);
    const float4 w3 = *(const float4*)(wrel + 3 * DIM + lane32 * 4);
    float wc[16];
#pragma unroll
    for (int i = 0; i < 16; ++i) wc[i] = wcls[i];
#pragma unroll
    for (int j = 0; j < 4; ++j) {
        wf[j].x = wc[j] * w0.x + wc[4 + j] * w1.x + wc[8 + j] * w2.x + wc[12 + j] * w3.x;
        wf[j].y = wc[j] * w0.y + wc[4 + j] * w1.y + wc[8 + j] * w2.y + wc[12 + j] * w3.y;
        wf[j].z = wc[j] * w0.z + wc[4 + j] * w1.z + wc[8 + j] * w2.z + wc[12 + j] * w3.z;
        wf[j].w = wc[j] * w0.w + wc[4 + j] * w1.w + wc[8 + j] * w2.w + wc[12 + j] * w3.w;
    }
}

__device__ __forceinline__ float4 dot4_bf16(ushort4 r, ushort4 p, const float4 wf[4])
{
    float qx = bf2f(r.x) * bf2f(p.x);
    float qy = bf2f(r.y) * bf2f(p.y);
    float qz = bf2f(r.z) * bf2f(p.z);
    float qw = bf2f(r.w) * bf2f(p.w);
    float4 b;
    b.x = qx * wf[0].x + qy * wf[0].y + qz * wf[0].z + qw * wf[0].w;
    b.y = qx * wf[1].x + qy * wf[1].y + qz * wf[1].z + qw * wf[1].w;
    b.z = qx * wf[2].x + qy * wf[2].y + qz * wf[2].z + qw * wf[2].w;
    b.w = qx * wf[3].x + qy * wf[3].y + qz * wf[3].z + qw * wf[3].w;
    return b;
}

// ---------- main kernel: bf16 gathers, ILP=4 edges per half-wave ----------
__global__ __launch_bounds__(256) void decoder_bf16_kernel(
    const unsigned short* __restrict__ rna,   // [N_RNA, D] bf16
    const unsigned short* __restrict__ prot,  // [N_PROT, D] bf16
    const int*   __restrict__ ridx,
    const int*   __restrict__ pidx,
    const float* __restrict__ wrel,
    const float* __restrict__ wcls,
    float*       __restrict__ out,
    int nEdges)
{
    const int lane32 = threadIdx.x & 31;
    const int hw     = (blockIdx.x * blockDim.x + threadIdx.x) >> 5;
    const int nhw    = (gridDim.x * blockDim.x) >> 5;

    float4 wf[4];
    load_wf(wrel, wcls, lane32, wf);

    const int cls   = ((lane32 & 1) << 1) | ((lane32 >> 1) & 1);
    const int lelem = lane32 * 4;

    const int nE4 = nEdges & ~3;
    for (int e0 = hw * 4; e0 + 3 < nE4 + 4 && e0 + 3 < nEdges; e0 += nhw * 4) {
        const int4 ri = *(const int4*)(ridx + e0);
        const int4 pi = *(const int4*)(pidx + e0);

        const ushort4 rA = *(const ushort4*)(rna  + (size_t)ri.x * DIM + lelem);
        const ushort4 pA = *(const ushort4*)(prot + (size_t)pi.x * DIM + lelem);
        const ushort4 rB = *(const ushort4*)(rna  + (size_t)ri.y * DIM + lelem);
        const ushort4 pB = *(const ushort4*)(prot + (size_t)pi.y * DIM + lelem);
        const ushort4 rC = *(const ushort4*)(rna  + (size_t)ri.z * DIM + lelem);
        const ushort4 pC = *(const ushort4*)(prot + (size_t)pi.z * DIM + lelem);
        const ushort4 rD = *(const ushort4*)(rna  + (size_t)ri.w * DIM + lelem);
        const ushort4 pD = *(const ushort4*)(prot + (size_t)pi.w * DIM + lelem);

        const float4 bA = dot4_bf16(rA, pA, wf);
        const float4 bB = dot4_bf16(rB, pB, wf);
        const float4 bC = dot4_bf16(rC, pC, wf);
        const float4 bD = dot4_bf16(rD, pD, wf);

        const float vA = reduce4(bA.x, bA.y, bA.z, bA.w, lane32);
        const float vB = reduce4(bB.x, bB.y, bB.z, bB.w, lane32);
        const float vC = reduce4(bC.x, bC.y, bC.z, bC.w, lane32);
        const float vD = reduce4(bD.x, bD.y, bD.z, bD.w, lane32);

        if (lane32 < 4) {
            out[(size_t)(e0 + 0) * NCLS + cls] = fmaxf(vA, 0.0f);
            out[(size_t)(e0 + 1) * NCLS + cls] = fmaxf(vB, 0.0f);
            out[(size_t)(e0 + 2) * NCLS + cls] = fmaxf(vC, 0.0f);
            out[(size_t)(e0 + 3) * NCLS + cls] = fmaxf(vD, 0.0f);
        }
    }
    // Tail (nEdges % 4 != 0) — not hit for E=500000, kept for safety.
    for (int e = nE4 + hw; e < nEdges; e += nhw) {
        const ushort4 r = *(const ushort4*)(rna  + (size_t)ridx[e] * DIM + lelem);
        const ushort4 p = *(const ushort4*)(prot + (size_t)pidx[e] * DIM + lelem);
        const float4 b = dot4_bf16(r, p, wf);
        const float v = reduce4(b.x, b.y, b.z, b.w, lane32);
        if (lane32 < 4) out[(size_t)e * NCLS + cls] = fmaxf(v, 0.0f);
    }
}

// ---------- fp32 fallback (R2 kernel) if workspace is too small ----------
__global__ __launch_bounds__(256) void decoder_f32_kernel(
    const float* __restrict__ rna, const float* __restrict__ prot,
    const int* __restrict__ ridx, const int* __restrict__ pidx,
    const float* __restrict__ wrel, const float* __restrict__ wcls,
    float* __restrict__ out, int nEdges)
{
    const int lane32 = threadIdx.x & 31;
    const int hw     = (blockIdx.x * blockDim.x + threadIdx.x) >> 5;
    const int nhw    = (gridDim.x * blockDim.x) >> 5;
    float4 wf[4];
    load_wf(wrel, wcls, lane32, wf);
    const int cls   = ((lane32 & 1) << 1) | ((lane32 >> 1) & 1);
    const int lelem = lane32 * 4;
    for (int e = hw; e < nEdges; e += nhw) {
        const float4 r = *(const float4*)(rna  + (size_t)ridx[e] * DIM + lelem);
        const float4 p = *(const float4*)(prot + (size_t)pidx[e] * DIM + lelem);
        float qx = r.x * p.x, qy = r.y * p.y, qz = r.z * p.z, qw = r.w * p.w;
        float b0 = qx * wf[0].x + qy * wf[0].y + qz * wf[0].z + qw * wf[0].w;
        float b1 = qx * wf[1].x + qy * wf[1].y + qz * wf[1].z + qw * wf[1].w;
        float b2 = qx * wf[2].x + qy * wf[2].y + qz * wf[2].z + qw * wf[2].w;
        float b3 = qx * wf[3].x + qy * wf[3].y + qz * wf[3].z + qw * wf[3].w;
        const float v = reduce4(b0, b1, b2, b3, lane32);
        if (lane32 < 4) out[(size_t)e * NCLS + cls] = fmaxf(v, 0.0f);
    }
}

extern "C" void kernel_launch(void* const* d_in, const int* in_sizes, int n_in,
                              void* d_out, int out_size, void* d_ws, size_t ws_size,
                              hipStream_t stream) {
    const float* rna  = (const float*)d_in[0];
    const float* prot = (const float*)d_in[1];
    const int*   ridx = (const int*)d_in[2];
    const int*   pidx = (const int*)d_in[3];
    const float* wrel = (const float*)d_in[4];
    const float* wcls = (const float*)d_in[5];
    float*       out  = (float*)d_out;

    const int nRnaElems  = in_sizes[0];   // 20000*128
    const int nProtElems = in_sizes[1];   // 5000*128
    const int nEdges     = in_sizes[2];   // 500000

    const size_t rnaBytes  = (size_t)nRnaElems * 2;   // bf16
    const size_t needBytes = rnaBytes + (size_t)nProtElems * 2;

    if (ws_size >= needBytes) {
        unsigned int* rnaBf  = (unsigned int*)d_ws;
        unsigned int* protBf = (unsigned int*)((char*)d_ws + rnaBytes);

        // fp32 -> bf16 conversion passes (each thread: 8 floats)
        {
            const int pairsR = nRnaElems / 2;
            const int blocksR = (pairsR / 4 + 255) / 256;
            hipLaunchKernelGGL(cvt_bf16_kernel, dim3(blocksR), dim3(256), 0, stream,
                               rna, rnaBf, pairsR);
            const int pairsP = nProtElems / 2;
            const int blocksP = (pairsP / 4 + 255) / 256;
            hipLaunchKernelGGL(cvt_bf16_kernel, dim3(blocksP), dim3(256), 0, stream,
                               prot, protBf, pairsP);
        }

        hipLaunchKernelGGL(decoder_bf16_kernel, dim3(8192), dim3(256), 0, stream,
                           (const unsigned short*)rnaBf, (const unsigned short*)protBf,
                           ridx, pidx, wrel, wcls, out, nEdges);
    } else {
        hipLaunchKernelGGL(decoder_f32_kernel, dim3(8192), dim3(256), 0, stream,
                           rna, prot, ridx, pidx, wrel, wcls, out, nEdges);
    }
}